// Round 1
// baseline (533.836 us; speedup 1.0000x reference)
//
#include <hip/hip_runtime.h>
#include <cmath>

#define B_ 8
#define N_ 4096
#define C_ 1024

// ws layout (doubles):
// e0: [0,16384)  e1: [16384,24576)  e2: [24576,28672)  e3: [28672,30720)
// thr: [30720,30724)  mix: [30724]

__device__ __forceinline__ double wred_d(double v) {
#pragma unroll
  for (int o = 32; o > 0; o >>= 1) v += __shfl_xor(v, o, 64);
  return v;
}

// ---------------- kernel 1: fp64 Haar energies ----------------
__global__ __launch_bounds__(256) void k_energy(const float* __restrict__ x,
                                                double* __restrict__ ws) {
  double* e0 = ws;
  double* e1 = ws + 16384;
  double* e2 = ws + 24576;
  double* e3 = ws + 28672;
  int g = blockIdx.x;          // 0..2047 = b*256 + t
  int b = g >> 8, t = g & 255; // t: group of 16 input rows
  int c4 = threadIdx.x << 2;
  const float* xp = x + ((size_t)(b * N_ + t * 16)) * C_ + c4;

  float xf[16][4];
#pragma unroll
  for (int i = 0; i < 16; ++i) {
    float4 v = *reinterpret_cast<const float4*>(xp + (size_t)i * C_);
    xf[i][0] = v.x; xf[i][1] = v.y; xf[i][2] = v.z; xf[i][3] = v.w;
  }
  double acc[15];
#pragma unroll
  for (int k = 0; k < 15; ++k) acc[k] = 0.0;

#pragma unroll
  for (int cc = 0; cc < 4; ++cc) {
    double l0[8];
#pragma unroll
    for (int j = 0; j < 8; ++j) {
      double xa = (double)xf[2 * j][cc], xb = (double)xf[2 * j + 1][cc];
      double d = (xa - xb) * 0.5;
      l0[j] = (xa + xb) * 0.5;
      acc[j] += d * d;
    }
    double l1[4];
#pragma unroll
    for (int j = 0; j < 4; ++j) {
      double d = (l0[2 * j] - l0[2 * j + 1]) * 0.5;
      l1[j] = (l0[2 * j] + l0[2 * j + 1]) * 0.5;
      acc[8 + j] += d * d;
    }
    double l2[2];
#pragma unroll
    for (int j = 0; j < 2; ++j) {
      double d = (l1[2 * j] - l1[2 * j + 1]) * 0.5;
      l2[j] = (l1[2 * j] + l1[2 * j + 1]) * 0.5;
      acc[12 + j] += d * d;
    }
    {
      double d = (l2[0] - l2[1]) * 0.5;
      acc[14] += d * d;
    }
  }

  __shared__ double part[15][4];
  int wv = threadIdx.x >> 6, ln = threadIdx.x & 63;
  double red[15];
#pragma unroll
  for (int k = 0; k < 15; ++k) red[k] = wred_d(acc[k]);
  if (ln == 0) {
#pragma unroll
    for (int k = 0; k < 15; ++k) part[k][wv] = red[k];
  }
  __syncthreads();
  int tid = threadIdx.x;
  if (tid < 15) {
    double s = (part[tid][0] + part[tid][1]) + (part[tid][2] + part[tid][3]);
    s *= (1.0 / 1024.0);  // mean over C
    if (tid < 8)       e0[b * 2048 + t * 8 + tid] = s;
    else if (tid < 12) e1[b * 1024 + t * 4 + (tid - 8)] = s;
    else if (tid < 14) e2[b * 512 + t * 2 + (tid - 12)] = s;
    else               e3[b * 256 + t] = s;
  }
}

// ---------------- kernel 2: exact quantile via radix-select + mix scalar ----
__global__ __launch_bounds__(256) void k_thr(const double* __restrict__ ws_e,
                                             double* __restrict__ thr_out,
                                             double* __restrict__ mix_out,
                                             const float* __restrict__ thrp,
                                             const float* __restrict__ cw1,
                                             const float* __restrict__ cw2,
                                             const float* __restrict__ cw3,
                                             const float* __restrict__ rw) {
  __shared__ unsigned int hist[256];
  __shared__ unsigned long long bpref;
  __shared__ int brank;
  __shared__ double pr[3][4];
  int tid = threadIdx.x;
  int blk = blockIdx.x;
  if (blk < 4) {
    int n = 16384 >> blk;
    int off = (blk == 0) ? 0 : (blk == 1) ? 16384 : (blk == 2) ? 24576 : 28672;
    const double* ep = ws_e + off;
    double q = (double)thrp[0];
    double idx = q * (double)(n - 1);
    int lo = (int)floor(idx);
    if (lo < 0) lo = 0;
    if (lo > n - 1) lo = n - 1;
    int hi = lo + 1;
    if (hi > n - 1) hi = n - 1;
    double frac = idx - (double)lo;
    double vv[2];
    int ranks[2] = {lo, hi};
    for (int s = 0; s < 2; ++s) {
      unsigned long long prefix = 0;
      int r = ranks[s];
      for (int pos = 56; pos >= 0; pos -= 8) {
        hist[tid] = 0;
        __syncthreads();
        unsigned long long hiMask = (pos == 56) ? 0ULL : (~0ULL << (pos + 8));
        for (int i = tid; i < n; i += 256) {
          unsigned long long u = (unsigned long long)__double_as_longlong(ep[i]);
          if ((u & hiMask) == prefix)
            atomicAdd(&hist[(unsigned int)(u >> pos) & 255u], 1u);
        }
        __syncthreads();
        if (tid == 0) {
          unsigned int cum = 0;
          int v = 0;
          for (; v < 256; ++v) {
            unsigned int c = hist[v];
            if (cum + c > (unsigned int)r) break;
            cum += c;
          }
          bpref = prefix | ((unsigned long long)v << pos);
          brank = r - (int)cum;
        }
        __syncthreads();
        prefix = bpref;
        r = brank;
        __syncthreads();
      }
      vv[s] = __longlong_as_double((long long)prefix);
    }
    if (tid == 0) thr_out[blk] = vv[0] * (1.0 - frac) + vv[1] * frac;
  } else {
    double s1 = 0, s2 = 0, s3 = 0;
    for (int i = tid; i < 1024; i += 256) {
      s1 += (double)cw1[i];
      s2 += (double)cw2[i];
      s3 += (double)cw3[i];
    }
    double r1 = wred_d(s1), r2 = wred_d(s2), r3 = wred_d(s3);
    int wv = tid >> 6, ln = tid & 63;
    if (ln == 0) { pr[0][wv] = r1; pr[1][wv] = r2; pr[2][wv] = r3; }
    __syncthreads();
    if (tid == 0) {
      double w1 = (pr[0][0] + pr[0][1] + pr[0][2] + pr[0][3]) / 1024.0;
      double w2 = (pr[1][0] + pr[1][1] + pr[1][2] + pr[1][3]) / 1024.0;
      double w3 = (pr[2][0] + pr[2][1] + pr[2][2] + pr[2][3]) / 1024.0;
      double sg = 1.0 / (1.0 + exp(-(double)rw[0]));
      mix_out[0] = (w1 + 0.5 * w2 + 0.2 * w3) * sg;
    }
  }
}

// ---------------- kernel 3: fused masked reconstruction --------------------
// One block = (batch b, tile t of 64 output rows). One thread = one channel.
__global__ __launch_bounds__(1024) void k_recon(const float* __restrict__ x,
                                                float* __restrict__ out,
                                                const double* __restrict__ ws,
                                                const float* __restrict__ swp) {
  const double* e0 = ws;
  const double* e1 = ws + 16384;
  const double* e2 = ws + 24576;
  const double* thr = ws + 30720;
  const double* mixp = ws + 30724;
  int blk = blockIdx.x;
  int b = blk >> 6, t = blk & 63;
  int tid = threadIdx.x;
  int c = tid;

  __shared__ float m0s[34], m1s[18], m2s[10];
  if (tid < 34) {
    float sw0 = 1.f / (1.f + __expf(-swp[0]));
    int row = 32 * t - 1 + tid;
    row = min(max(row, 0), 2047);
    m0s[tid] = (e0[b * 2048 + row] > thr[0]) ? sw0 : 0.f;
  }
  if (tid < 18) {
    float sw1 = 1.f / (1.f + __expf(-swp[1]));
    int row = 16 * t - 1 + tid;
    row = min(max(row, 0), 1023);
    m1s[tid] = (e1[b * 1024 + row] > thr[1]) ? sw1 : 0.f;
  }
  if (tid < 10) {
    float sw2 = 1.f / (1.f + __expf(-swp[2]));
    int row = 8 * t - 1 + tid;
    row = min(max(row, 0), 511);
    m2s[tid] = (e2[b * 512 + row] > thr[2]) ? sw2 : 0.f;
  }
  __syncthreads();
  float sw3 = 1.f / (1.f + __expf(-swp[3]));
  float mix = (float)mixp[0];

  const float* xp = x + (size_t)b * N_ * C_ + c;

  // streaming Haar cascade: persistent detail halos + a3
  float d0[34], d1[18], d2[10], a3[6];
  float c0 = 0.f, c1 = 0.f, c2 = 0.f;
#pragma unroll
  for (int i = 0; i < 48; ++i) {
    int qrow = 32 * t - 8 + i;  // level-0 approx global row
    int r0 = min(max(2 * qrow, 0), N_ - 1);
    int r1 = min(max(2 * qrow + 1, 0), N_ - 1);
    float xa = xp[(size_t)r0 * C_];
    float xb = xp[(size_t)r1 * C_];
    float a0 = (xa + xb) * 0.5f;
    if (i >= 7 && i < 41) d0[i - 7] = (xa - xb) * 0.5f;  // rows 32t-1 .. 32t+32
    if ((i & 1) == 0)
      c0 = a0;
    else {
      int i1 = i >> 1;  // a1 row 16t-4+i1
      float a1 = (c0 + a0) * 0.5f;
      if (i1 >= 3 && i1 < 21) d1[i1 - 3] = (c0 - a0) * 0.5f;  // rows 16t-1..16t+16
      if ((i1 & 1) == 0)
        c1 = a1;
      else {
        int i2 = i1 >> 1;  // a2 row 8t-2+i2
        float a2 = (c1 + a1) * 0.5f;
        if (i2 >= 1 && i2 < 11) d2[i2 - 1] = (c1 - a1) * 0.5f;  // rows 8t-1..8t+8
        if ((i2 & 1) == 0)
          c2 = a2;
        else
          a3[i2 >> 1] = (c2 + a2) * 0.5f;  // rows 4t-1..4t+4
      }
    }
  }

  float rec256[6];
#pragma unroll
  for (int i = 0; i < 6; ++i) rec256[i] = a3[i] * sw3;

  // up 256->512 (+ masked d2). rows r = 8t-1+j (base odd).
  float rec512[10];
#pragma unroll
  for (int j = 0; j < 10; ++j) {
    float v;
    if ((j & 1) == 0) {  // r odd: out[2s+1] = .75 in[s] + .25 in[s+1]
      int s = 4 * t - 1 + (j >> 1);
      int sl = j >> 1;
      v = 0.75f * rec256[sl] + 0.25f * rec256[sl + 1];
      if (s == 255) v = rec256[sl];
    } else {  // r even: out[2s] = .25 in[s-1] + .75 in[s]
      int s = 4 * t + (j >> 1);
      int sl = (j >> 1) + 1;
      v = 0.25f * rec256[sl - 1] + 0.75f * rec256[sl];
      if (s == 0) v = rec256[sl];
    }
    rec512[j] = v + d2[j] * m2s[j];
  }

  // up 512->1024 (+ masked d1). rows p = 16t-1+j.
  float rec1024[18];
#pragma unroll
  for (int j = 0; j < 18; ++j) {
    float v;
    if ((j & 1) == 0) {
      int s = 8 * t - 1 + (j >> 1);
      int sl = j >> 1;
      v = 0.75f * rec512[sl] + 0.25f * rec512[sl + 1];
      if (s == 511) v = rec512[sl];
    } else {
      int s = 8 * t + (j >> 1);
      int sl = (j >> 1) + 1;
      v = 0.25f * rec512[sl - 1] + 0.75f * rec512[sl];
      if (s == 0) v = rec512[sl];
    }
    rec1024[j] = v + d1[j] * m1s[j];
  }

  // up 1024->2048 (+ masked d0). rows m = 32t-1+j.
  float rec2048[34];
#pragma unroll
  for (int j = 0; j < 34; ++j) {
    float v;
    if ((j & 1) == 0) {
      int s = 16 * t - 1 + (j >> 1);
      int sl = j >> 1;
      v = 0.75f * rec1024[sl] + 0.25f * rec1024[sl + 1];
      if (s == 1023) v = rec1024[sl];
    } else {
      int s = 16 * t + (j >> 1);
      int sl = (j >> 1) + 1;
      v = 0.25f * rec1024[sl - 1] + 0.75f * rec1024[sl];
      if (s == 0) v = rec1024[sl];
    }
    rec2048[j] = v + d0[j] * m0s[j];
  }

  // final up 2048->4096, scale, store. rows g = 64t+j (base even).
  float* op = out + ((size_t)(b * N_ + 64 * t)) * C_ + c;
#pragma unroll
  for (int j = 0; j < 64; ++j) {
    float v;
    if ((j & 1) == 0) {  // g even: out[2s] = .25 in[s-1] + .75 in[s]
      int s = 32 * t + (j >> 1);
      int sl = (j >> 1) + 1;
      v = 0.25f * rec2048[sl - 1] + 0.75f * rec2048[sl];
      if (s == 0) v = rec2048[sl];
    } else {  // g odd: out[2s+1] = .75 in[s] + .25 in[s+1]
      int s = 32 * t + (j >> 1);
      int sl = (j >> 1) + 1;
      v = 0.75f * rec2048[sl] + 0.25f * rec2048[sl + 1];
      if (s == 2047) v = rec2048[sl];
    }
    op[(size_t)j * C_] = v * mix;
  }
}

extern "C" void kernel_launch(void* const* d_in, const int* in_sizes, int n_in,
                              void* d_out, int out_size, void* d_ws, size_t ws_size,
                              hipStream_t stream) {
  const float* x = (const float*)d_in[0];
  const float* cw1 = (const float*)d_in[1];
  const float* cw2 = (const float*)d_in[2];
  const float* cw3 = (const float*)d_in[3];
  const float* thrp = (const float*)d_in[4];
  const float* sws = (const float*)d_in[5];
  const float* rw = (const float*)d_in[6];
  float* out = (float*)d_out;
  double* ws = (double*)d_ws;

  hipLaunchKernelGGL(k_energy, dim3(2048), dim3(256), 0, stream, x, ws);
  hipLaunchKernelGGL(k_thr, dim3(5), dim3(256), 0, stream, ws, ws + 30720,
                     ws + 30724, thrp, cw1, cw2, cw3, rw);
  hipLaunchKernelGGL(k_recon, dim3(512), dim3(1024), 0, stream, x, out, ws, sws);
}

// Round 2
// 455.769 us; speedup vs baseline: 1.1713x; 1.1713x over previous
//
#include <hip/hip_runtime.h>
#include <cmath>

#define B_ 8
#define N_ 4096
#define C_ 1024

// ws layout (doubles):
// e0: [0,16384)  e1: [16384,24576)  e2: [24576,28672)  e3: [28672,30720)
// vv: [30720,30728)  (vv[2*s] = value at rank lo, vv[2*s+1] = value at rank hi)
// mix: [30728]

__device__ __forceinline__ double wred_d(double v) {
#pragma unroll
  for (int o = 32; o > 0; o >>= 1) v += __shfl_xor(v, o, 64);
  return v;
}

// quantile index helpers (q in [0,0.5] here, but clamp anyway)
__device__ __forceinline__ void qidx(double q, int n, int& lo, int& hi, double& frac) {
  double idx = q * (double)(n - 1);
  lo = (int)floor(idx);
  if (lo < 0) lo = 0;
  if (lo > n - 1) lo = n - 1;
  hi = lo + 1;
  if (hi > n - 1) hi = n - 1;
  frac = idx - (double)lo;
}

// ---------------- kernel 1: fp64 Haar energies ----------------
__global__ __launch_bounds__(256) void k_energy(const float* __restrict__ x,
                                                double* __restrict__ ws) {
  double* e0 = ws;
  double* e1 = ws + 16384;
  double* e2 = ws + 24576;
  double* e3 = ws + 28672;
  int g = blockIdx.x;          // 0..2047 = b*256 + t
  int b = g >> 8, t = g & 255; // t: group of 16 input rows
  int c4 = threadIdx.x << 2;
  const float* xp = x + ((size_t)(b * N_ + t * 16)) * C_ + c4;

  float xf[16][4];
#pragma unroll
  for (int i = 0; i < 16; ++i) {
    float4 v = *reinterpret_cast<const float4*>(xp + (size_t)i * C_);
    xf[i][0] = v.x; xf[i][1] = v.y; xf[i][2] = v.z; xf[i][3] = v.w;
  }
  double acc[15];
#pragma unroll
  for (int k = 0; k < 15; ++k) acc[k] = 0.0;

#pragma unroll
  for (int cc = 0; cc < 4; ++cc) {
    double l0[8];
#pragma unroll
    for (int j = 0; j < 8; ++j) {
      double xa = (double)xf[2 * j][cc], xb = (double)xf[2 * j + 1][cc];
      double d = (xa - xb) * 0.5;
      l0[j] = (xa + xb) * 0.5;
      acc[j] += d * d;
    }
    double l1[4];
#pragma unroll
    for (int j = 0; j < 4; ++j) {
      double d = (l0[2 * j] - l0[2 * j + 1]) * 0.5;
      l1[j] = (l0[2 * j] + l0[2 * j + 1]) * 0.5;
      acc[8 + j] += d * d;
    }
    double l2[2];
#pragma unroll
    for (int j = 0; j < 2; ++j) {
      double d = (l1[2 * j] - l1[2 * j + 1]) * 0.5;
      l2[j] = (l1[2 * j] + l1[2 * j + 1]) * 0.5;
      acc[12 + j] += d * d;
    }
    {
      double d = (l2[0] - l2[1]) * 0.5;
      acc[14] += d * d;
    }
  }

  __shared__ double part[15][4];
  int wv = threadIdx.x >> 6, ln = threadIdx.x & 63;
  double red[15];
#pragma unroll
  for (int k = 0; k < 15; ++k) red[k] = wred_d(acc[k]);
  if (ln == 0) {
#pragma unroll
    for (int k = 0; k < 15; ++k) part[k][wv] = red[k];
  }
  __syncthreads();
  int tid = threadIdx.x;
  if (tid < 15) {
    double s = (part[tid][0] + part[tid][1]) + (part[tid][2] + part[tid][3]);
    s *= (1.0 / 1024.0);  // mean over C
    if (tid < 8)       e0[b * 2048 + t * 8 + tid] = s;
    else if (tid < 12) e1[b * 1024 + t * 4 + (tid - 8)] = s;
    else if (tid < 14) e2[b * 512 + t * 2 + (tid - 12)] = s;
    else               e3[b * 256 + t] = s;
  }
}

// ---------------- kernel 2: parallel exact rank-select + mix scalar --------
// Blocks 0..63: scale0 (n=16384), 64..95: scale1, 96..111: scale2,
// 112..119: scale3, 120: mix scalar.
// Each scale-block ranks 256 elements; 1024 threads = 256 i's x 4 j-quarters.
// Stable rank (index tie-break) => ranks form a permutation => ranks lo and
// hi each hit exactly once => single plain store, no race.
__global__ __launch_bounds__(1024) void k_rank(const double* __restrict__ ws_e,
                                               double* __restrict__ vv_out,
                                               double* __restrict__ mix_out,
                                               const float* __restrict__ thrp,
                                               const float* __restrict__ cw1,
                                               const float* __restrict__ cw2,
                                               const float* __restrict__ cw3,
                                               const float* __restrict__ rw) {
  int blk = blockIdx.x;
  int t = threadIdx.x;

  if (blk < 120) {
    int s, ibase;
    if (blk < 64)       { s = 0; ibase = blk * 256; }
    else if (blk < 96)  { s = 1; ibase = (blk - 64) * 256; }
    else if (blk < 112) { s = 2; ibase = (blk - 96) * 256; }
    else                { s = 3; ibase = (blk - 112) * 256; }
    int n = 16384 >> s;
    int off = (s == 0) ? 0 : (s == 1) ? 16384 : (s == 2) ? 24576 : 28672;
    const double* ep = ws_e + off;

    int il = t & 255;   // local i
    int q = t >> 8;     // j-quarter
    int i = ibase + il;
    unsigned long long ui = (unsigned long long)__double_as_longlong(ep[i]);

    __shared__ unsigned long long lv[1024];
    __shared__ int pc[1024];
    int n4 = n >> 2;
    int jbase = q * n4;
    int cnt = 0;
    for (int st = 0; st < n4; st += 256) {
      lv[t] = (unsigned long long)__double_as_longlong(ep[jbase + st + il]);
      __syncthreads();
      int segbase = jbase + st;
      const unsigned long long* seg = &lv[q << 8];
#pragma unroll 8
      for (int jj = 0; jj < 256; ++jj) {
        unsigned long long uj = seg[jj];
        int jglob = segbase + jj;
        cnt += (uj < ui) || (uj == ui && jglob < i);
      }
      __syncthreads();
    }
    pc[t] = cnt;
    __syncthreads();
    if (t < 256) {
      int rank = pc[t] + pc[t + 256] + pc[t + 512] + pc[t + 768];
      int lo, hi; double frac;
      qidx((double)thrp[0], n, lo, hi, frac);
      double v = __longlong_as_double((long long)ui);
      if (rank == lo) vv_out[2 * s] = v;
      if (rank == hi) vv_out[2 * s + 1] = v;
    }
  } else {
    // mix scalar: mean(cw1) + 0.5*mean(cw2) + 0.2*mean(cw3), times sigmoid(rw)
    __shared__ double pr[3][16];
    double s1 = (double)cw1[t];
    double s2 = (double)cw2[t];
    double s3 = (double)cw3[t];
    double r1 = wred_d(s1), r2 = wred_d(s2), r3 = wred_d(s3);
    int wv = t >> 6, ln = t & 63;
    if (ln == 0) { pr[0][wv] = r1; pr[1][wv] = r2; pr[2][wv] = r3; }
    __syncthreads();
    if (t == 0) {
      double w1 = 0, w2 = 0, w3 = 0;
#pragma unroll
      for (int k = 0; k < 16; ++k) { w1 += pr[0][k]; w2 += pr[1][k]; w3 += pr[2][k]; }
      w1 /= 1024.0; w2 /= 1024.0; w3 /= 1024.0;
      double sg = 1.0 / (1.0 + exp(-(double)rw[0]));
      mix_out[0] = (w1 + 0.5 * w2 + 0.2 * w3) * sg;
    }
  }
}

// ---------------- kernel 3: fused masked reconstruction --------------------
// One block = (batch b, tile t of 64 output rows, channel-quarter cq).
// 256 threads: one thread = one channel column. 256-thread blocks keep the
// VGPR cap at 512 (1024-thread blocks cap at 128 -> this kernel would spill).
__global__ __launch_bounds__(256) void k_recon(const float* __restrict__ x,
                                               float* __restrict__ out,
                                               const double* __restrict__ ws,
                                               const float* __restrict__ swp,
                                               const float* __restrict__ thrp) {
  const double* e0 = ws;
  const double* e1 = ws + 16384;
  const double* e2 = ws + 24576;
  const double* vv = ws + 30720;
  const double* mixp = ws + 30728;
  int blk = blockIdx.x;
  int b = blk >> 8;
  int rem = blk & 255;
  int t = rem >> 2;
  int cq = rem & 3;
  int tid = threadIdx.x;
  int c = cq * 256 + tid;

  __shared__ float m0s[34], m1s[18], m2s[10];
  if (tid < 34) {
    int lo, hi; double frac;
    qidx((double)thrp[0], 16384, lo, hi, frac);
    double thr0 = vv[0] * (1.0 - frac) + vv[1] * frac;
    float sw0 = 1.f / (1.f + __expf(-swp[0]));
    int row = 32 * t - 1 + tid;
    row = min(max(row, 0), 2047);
    m0s[tid] = (e0[b * 2048 + row] > thr0) ? sw0 : 0.f;
  }
  if (tid < 18) {
    int lo, hi; double frac;
    qidx((double)thrp[0], 8192, lo, hi, frac);
    double thr1 = vv[2] * (1.0 - frac) + vv[3] * frac;
    float sw1 = 1.f / (1.f + __expf(-swp[1]));
    int row = 16 * t - 1 + tid;
    row = min(max(row, 0), 1023);
    m1s[tid] = (e1[b * 1024 + row] > thr1) ? sw1 : 0.f;
  }
  if (tid < 10) {
    int lo, hi; double frac;
    qidx((double)thrp[0], 4096, lo, hi, frac);
    double thr2 = vv[4] * (1.0 - frac) + vv[5] * frac;
    float sw2 = 1.f / (1.f + __expf(-swp[2]));
    int row = 8 * t - 1 + tid;
    row = min(max(row, 0), 511);
    m2s[tid] = (e2[b * 512 + row] > thr2) ? sw2 : 0.f;
  }
  __syncthreads();
  float sw3 = 1.f / (1.f + __expf(-swp[3]));
  float mix = (float)mixp[0];

  const float* xp = x + (size_t)b * N_ * C_ + c;

  // streaming Haar cascade: persistent detail halos + a3
  float d0[34], d1[18], d2[10], a3[6];
  float c0 = 0.f, c1 = 0.f, c2 = 0.f;
#pragma unroll
  for (int i = 0; i < 48; ++i) {
    int qrow = 32 * t - 8 + i;  // level-0 approx global row
    int r0 = min(max(2 * qrow, 0), N_ - 1);
    int r1 = min(max(2 * qrow + 1, 0), N_ - 1);
    float xa = xp[(size_t)r0 * C_];
    float xb = xp[(size_t)r1 * C_];
    float a0 = (xa + xb) * 0.5f;
    if (i >= 7 && i < 41) d0[i - 7] = (xa - xb) * 0.5f;  // rows 32t-1 .. 32t+32
    if ((i & 1) == 0)
      c0 = a0;
    else {
      int i1 = i >> 1;  // a1 row 16t-4+i1
      float a1 = (c0 + a0) * 0.5f;
      if (i1 >= 3 && i1 < 21) d1[i1 - 3] = (c0 - a0) * 0.5f;  // rows 16t-1..16t+16
      if ((i1 & 1) == 0)
        c1 = a1;
      else {
        int i2 = i1 >> 1;  // a2 row 8t-2+i2
        float a2 = (c1 + a1) * 0.5f;
        if (i2 >= 1 && i2 < 11) d2[i2 - 1] = (c1 - a1) * 0.5f;  // rows 8t-1..8t+8
        if ((i2 & 1) == 0)
          c2 = a2;
        else
          a3[i2 >> 1] = (c2 + a2) * 0.5f;  // rows 4t-1..4t+4
      }
    }
  }

  float rec256[6];
#pragma unroll
  for (int i = 0; i < 6; ++i) rec256[i] = a3[i] * sw3;

  // up 256->512 (+ masked d2). rows r = 8t-1+j (base odd).
  float rec512[10];
#pragma unroll
  for (int j = 0; j < 10; ++j) {
    float v;
    if ((j & 1) == 0) {  // r odd: out[2s+1] = .75 in[s] + .25 in[s+1]
      int s = 4 * t - 1 + (j >> 1);
      int sl = j >> 1;
      v = 0.75f * rec256[sl] + 0.25f * rec256[sl + 1];
      if (s == 255) v = rec256[sl];
    } else {  // r even: out[2s] = .25 in[s-1] + .75 in[s]
      int s = 4 * t + (j >> 1);
      int sl = (j >> 1) + 1;
      v = 0.25f * rec256[sl - 1] + 0.75f * rec256[sl];
      if (s == 0) v = rec256[sl];
    }
    rec512[j] = v + d2[j] * m2s[j];
  }

  // up 512->1024 (+ masked d1). rows p = 16t-1+j.
  float rec1024[18];
#pragma unroll
  for (int j = 0; j < 18; ++j) {
    float v;
    if ((j & 1) == 0) {
      int s = 8 * t - 1 + (j >> 1);
      int sl = j >> 1;
      v = 0.75f * rec512[sl] + 0.25f * rec512[sl + 1];
      if (s == 511) v = rec512[sl];
    } else {
      int s = 8 * t + (j >> 1);
      int sl = (j >> 1) + 1;
      v = 0.25f * rec512[sl - 1] + 0.75f * rec512[sl];
      if (s == 0) v = rec512[sl];
    }
    rec1024[j] = v + d1[j] * m1s[j];
  }

  // up 1024->2048 (+ masked d0). rows m = 32t-1+j.
  float rec2048[34];
#pragma unroll
  for (int j = 0; j < 34; ++j) {
    float v;
    if ((j & 1) == 0) {
      int s = 16 * t - 1 + (j >> 1);
      int sl = j >> 1;
      v = 0.75f * rec1024[sl] + 0.25f * rec1024[sl + 1];
      if (s == 1023) v = rec1024[sl];
    } else {
      int s = 16 * t + (j >> 1);
      int sl = (j >> 1) + 1;
      v = 0.25f * rec1024[sl - 1] + 0.75f * rec1024[sl];
      if (s == 0) v = rec1024[sl];
    }
    rec2048[j] = v + d0[j] * m0s[j];
  }

  // final up 2048->4096, scale, store. rows g = 64t+j (base even).
  float* op = out + ((size_t)(b * N_ + 64 * t)) * C_ + c;
#pragma unroll
  for (int j = 0; j < 64; ++j) {
    float v;
    if ((j & 1) == 0) {  // g even: out[2s] = .25 in[s-1] + .75 in[s]
      int s = 32 * t + (j >> 1);
      int sl = (j >> 1) + 1;
      v = 0.25f * rec2048[sl - 1] + 0.75f * rec2048[sl];
      if (s == 0) v = rec2048[sl];
    } else {  // g odd: out[2s+1] = .75 in[s] + .25 in[s+1]
      int s = 32 * t + (j >> 1);
      int sl = (j >> 1) + 1;
      v = 0.75f * rec2048[sl] + 0.25f * rec2048[sl + 1];
      if (s == 2047) v = rec2048[sl];
    }
    op[(size_t)j * C_] = v * mix;
  }
}

extern "C" void kernel_launch(void* const* d_in, const int* in_sizes, int n_in,
                              void* d_out, int out_size, void* d_ws, size_t ws_size,
                              hipStream_t stream) {
  const float* x = (const float*)d_in[0];
  const float* cw1 = (const float*)d_in[1];
  const float* cw2 = (const float*)d_in[2];
  const float* cw3 = (const float*)d_in[3];
  const float* thrp = (const float*)d_in[4];
  const float* sws = (const float*)d_in[5];
  const float* rw = (const float*)d_in[6];
  float* out = (float*)d_out;
  double* ws = (double*)d_ws;

  hipLaunchKernelGGL(k_energy, dim3(2048), dim3(256), 0, stream, x, ws);
  hipLaunchKernelGGL(k_rank, dim3(121), dim3(1024), 0, stream, ws, ws + 30720,
                     ws + 30728, thrp, cw1, cw2, cw3, rw);
  hipLaunchKernelGGL(k_recon, dim3(2048), dim3(256), 0, stream, x, out, ws, sws,
                     thrp);
}

// Round 3
// 312.919 us; speedup vs baseline: 1.7060x; 1.4565x over previous
//
#include <hip/hip_runtime.h>
#include <cmath>

#define B_ 8
#define N_ 4096
#define C_ 1024

// ws layout (doubles):
// e0: [0,16384)  e1: [16384,24576)  e2: [24576,28672)  e3: [28672,30720) (unused)
// vv: [30720,30728)  (vv[2*s] = value at rank lo, vv[2*s+1] = value at rank hi)
// mix: [30728]

__device__ __forceinline__ double wred_d(double v) {
#pragma unroll
  for (int o = 32; o > 0; o >>= 1) v += __shfl_xor(v, o, 64);
  return v;
}

__device__ __forceinline__ void qidx(double q, int n, int& lo, int& hi, double& frac) {
  double idx = q * (double)(n - 1);
  lo = (int)floor(idx);
  if (lo < 0) lo = 0;
  if (lo > n - 1) lo = n - 1;
  hi = lo + 1;
  if (hi > n - 1) hi = n - 1;
  frac = idx - (double)lo;
}

// ---------------- kernel 1: fp64 Haar energies (streaming, low VGPR) -------
__global__ __launch_bounds__(256) void k_energy(const float* __restrict__ x,
                                                double* __restrict__ ws) {
  double* e0 = ws;
  double* e1 = ws + 16384;
  double* e2 = ws + 24576;
  int g = blockIdx.x;          // 0..2047 = b*256 + t
  int b = g >> 8, t = g & 255; // t: group of 16 input rows
  int c4 = threadIdx.x << 2;
  const float* xp = x + ((size_t)(b * N_ + t * 16)) * C_ + c4;

  double acc[15];
#pragma unroll
  for (int k = 0; k < 15; ++k) acc[k] = 0.0;

  // streaming cascade state per channel lane (4 channels via float4)
  double xprev[4], a0p[4], a1p[4], a2p[4];
#pragma unroll
  for (int i = 0; i < 16; ++i) {
    float4 v = *reinterpret_cast<const float4*>(xp + (size_t)i * C_);
    double f[4] = {(double)v.x, (double)v.y, (double)v.z, (double)v.w};
    if ((i & 1) == 0) {
#pragma unroll
      for (int cc = 0; cc < 4; ++cc) xprev[cc] = f[cc];
    } else {
      int j0 = i >> 1;
      double a0[4];
#pragma unroll
      for (int cc = 0; cc < 4; ++cc) {
        double d = (xprev[cc] - f[cc]) * 0.5;
        a0[cc] = (xprev[cc] + f[cc]) * 0.5;
        acc[j0] += d * d;
      }
      if ((j0 & 1) == 0) {
#pragma unroll
        for (int cc = 0; cc < 4; ++cc) a0p[cc] = a0[cc];
      } else {
        int j1 = j0 >> 1;
        double a1[4];
#pragma unroll
        for (int cc = 0; cc < 4; ++cc) {
          double d = (a0p[cc] - a0[cc]) * 0.5;
          a1[cc] = (a0p[cc] + a0[cc]) * 0.5;
          acc[8 + j1] += d * d;
        }
        if ((j1 & 1) == 0) {
#pragma unroll
          for (int cc = 0; cc < 4; ++cc) a1p[cc] = a1[cc];
        } else {
          int j2 = j1 >> 1;
          double a2[4];
#pragma unroll
          for (int cc = 0; cc < 4; ++cc) {
            double d = (a1p[cc] - a1[cc]) * 0.5;
            a2[cc] = (a1p[cc] + a1[cc]) * 0.5;
            acc[12 + j2] += d * d;
          }
          if ((j2 & 1) == 0) {
#pragma unroll
            for (int cc = 0; cc < 4; ++cc) a2p[cc] = a2[cc];
          } else {
#pragma unroll
            for (int cc = 0; cc < 4; ++cc) {
              double d = (a2p[cc] - a2[cc]) * 0.5;
              acc[14] += d * d;
            }
          }
        }
      }
    }
  }

  __shared__ double part[15][4];
  int wv = threadIdx.x >> 6, ln = threadIdx.x & 63;
  double red[15];
#pragma unroll
  for (int k = 0; k < 15; ++k) red[k] = wred_d(acc[k]);
  if (ln == 0) {
#pragma unroll
    for (int k = 0; k < 15; ++k) part[k][wv] = red[k];
  }
  __syncthreads();
  int tid = threadIdx.x;
  if (tid < 14) {
    double s = (part[tid][0] + part[tid][1]) + (part[tid][2] + part[tid][3]);
    s *= (1.0 / 1024.0);  // mean over C
    if (tid < 8)       e0[b * 2048 + t * 8 + tid] = s;
    else if (tid < 12) e1[b * 1024 + t * 4 + (tid - 8)] = s;
    else               e2[b * 512 + t * 2 + (tid - 12)] = s;
    // e3 (tid==14) dropped: thr3/mask3 never used in reconstruction
  }
}

// ---------------- kernel 2: histogram select (O(n)) + mix scalar -----------
// Blocks 0..2: exact fp64 order statistics (ranks lo,hi) per scale via
// LDS histogram on (exp | top-8 mantissa) bits -> candidate bin ~600 elems
// -> exact stable rank among candidates. Block 3: mix scalar.
__global__ __launch_bounds__(1024) void k_select(const double* __restrict__ ws_e,
                                                 double* __restrict__ vv_out,
                                                 double* __restrict__ mix_out,
                                                 const float* __restrict__ thrp,
                                                 const float* __restrict__ cw1,
                                                 const float* __restrict__ cw2,
                                                 const float* __restrict__ cw3,
                                                 const float* __restrict__ rw) {
  const int NB = 6144;       // 24 exponents x 256 mantissa-msb bins
  const int CMAX = 2048;     // candidate buffer
  __shared__ unsigned int hist[NB];
  __shared__ unsigned long long cand[CMAX];
  __shared__ int candIdx[CMAX];
  __shared__ int ps[1024];
  __shared__ int sb_bin[2];
  __shared__ int sb_base[2];
  __shared__ unsigned int ccount;
  __shared__ double pr[3][16];

  int blk = blockIdx.x;
  int t = threadIdx.x;

  if (blk < 3) {
    int s = blk;
    int n = 16384 >> s;
    int off = (s == 0) ? 0 : (s == 1) ? 16384 : 24576;
    const double* ep = ws_e + off;

    for (int i = t; i < NB; i += 1024) hist[i] = 0;
    __syncthreads();
    for (int i = t; i < n; i += 1024) {
      unsigned long long u = (unsigned long long)__double_as_longlong(ep[i]);
      int raw = (int)(u >> 44) - (1008 << 8);
      int bin = raw < 0 ? 0 : (raw > NB - 1 ? NB - 1 : raw);
      atomicAdd(&hist[bin], 1u);
    }
    __syncthreads();

    // prefix-scan over 1024 chunks of 6 bins
    int s0 = 0;
#pragma unroll
    for (int k = 0; k < 6; ++k) s0 += (int)hist[t * 6 + k];
    ps[t] = s0;
    __syncthreads();
    for (int o = 1; o < 1024; o <<= 1) {
      int add = (t >= o) ? ps[t - o] : 0;
      __syncthreads();
      ps[t] += add;
      __syncthreads();
    }
    int excl = ps[t] - s0;

    int lo, hi; double frac;
    qidx((double)thrp[0], n, lo, hi, frac);
    int ranks[2] = {lo, hi};
#pragma unroll
    for (int r = 0; r < 2; ++r) {
      int run = excl;
#pragma unroll
      for (int k = 0; k < 6; ++k) {
        int c = (int)hist[t * 6 + k];
        if (ranks[r] >= run && ranks[r] < run + c) {
          sb_bin[r] = t * 6 + k;
          sb_base[r] = run;
        }
        run += c;
      }
    }
    __syncthreads();

    for (int r = 0; r < 2; ++r) {
      int b = sb_bin[r];
      int rr = ranks[r] - sb_base[r];
      int m = (int)hist[b];
      if (t == 0) ccount = 0;
      __syncthreads();
      if (m <= CMAX) {
        for (int i = t; i < n; i += 1024) {
          unsigned long long u = (unsigned long long)__double_as_longlong(ep[i]);
          int raw = (int)(u >> 44) - (1008 << 8);
          int bin = raw < 0 ? 0 : (raw > NB - 1 ? NB - 1 : raw);
          if (bin == b) {
            unsigned int p = atomicAdd(&ccount, 1u);
            cand[p] = u;
            candIdx[p] = i;
          }
        }
        __syncthreads();
        for (int k = t; k < m; k += 1024) {
          unsigned long long uk = cand[k];
          int ik = candIdx[k];
          int cl = 0;
          for (int j = 0; j < m; ++j) {
            unsigned long long uj = cand[j];
            cl += (uj < uk) || (uj == uk && candIdx[j] < ik);
          }
          if (cl == rr) vv_out[2 * s + r] = __longlong_as_double((long long)uk);
        }
      } else {
        // robustness fallback (never expected): full-array stable rank
        for (int i = t; i < n; i += 1024) {
          unsigned long long ui = (unsigned long long)__double_as_longlong(ep[i]);
          int raw = (int)(ui >> 44) - (1008 << 8);
          int bin = raw < 0 ? 0 : (raw > NB - 1 ? NB - 1 : raw);
          if (bin != b) continue;
          int cl = 0;
          for (int j = 0; j < n; ++j) {
            unsigned long long uj = (unsigned long long)__double_as_longlong(ep[j]);
            cl += (uj < ui) || (uj == ui && j < i);
          }
          if (cl == ranks[r]) vv_out[2 * s + r] = __longlong_as_double((long long)ui);
        }
      }
      __syncthreads();
    }
  } else {
    // mix scalar: (mean(cw1) + 0.5*mean(cw2) + 0.2*mean(cw3)) * sigmoid(rw)
    double s1 = (double)cw1[t];
    double s2 = (double)cw2[t];
    double s3 = (double)cw3[t];
    double r1 = wred_d(s1), r2 = wred_d(s2), r3 = wred_d(s3);
    int wv = t >> 6, ln = t & 63;
    if (ln == 0) { pr[0][wv] = r1; pr[1][wv] = r2; pr[2][wv] = r3; }
    __syncthreads();
    if (t == 0) {
      double w1 = 0, w2 = 0, w3 = 0;
#pragma unroll
      for (int k = 0; k < 16; ++k) { w1 += pr[0][k]; w2 += pr[1][k]; w3 += pr[2][k]; }
      w1 /= 1024.0; w2 /= 1024.0; w3 /= 1024.0;
      double sg = 1.0 / (1.0 + exp(-(double)rw[0]));
      mix_out[0] = (w1 + 0.5 * w2 + 0.2 * w3) * sg;
    }
  }
}

// ---------------- kernel 3: fused masked reconstruction --------------------
// One block = (batch b, tile t of 64 output rows, channel-quarter cq).
__global__ __launch_bounds__(256) void k_recon(const float* __restrict__ x,
                                               float* __restrict__ out,
                                               const double* __restrict__ ws,
                                               const float* __restrict__ swp,
                                               const float* __restrict__ thrp) {
  const double* e0 = ws;
  const double* e1 = ws + 16384;
  const double* e2 = ws + 24576;
  const double* vv = ws + 30720;
  const double* mixp = ws + 30728;
  int blk = blockIdx.x;
  int b = blk >> 8;
  int rem = blk & 255;
  int t = rem >> 2;
  int cq = rem & 3;
  int tid = threadIdx.x;
  int c = cq * 256 + tid;

  __shared__ float m0s[34], m1s[18], m2s[10];
  if (tid < 34) {
    int lo, hi; double frac;
    qidx((double)thrp[0], 16384, lo, hi, frac);
    double thr0 = vv[0] * (1.0 - frac) + vv[1] * frac;
    float sw0 = 1.f / (1.f + __expf(-swp[0]));
    int row = 32 * t - 1 + tid;
    row = min(max(row, 0), 2047);
    m0s[tid] = (e0[b * 2048 + row] > thr0) ? sw0 : 0.f;
  }
  if (tid < 18) {
    int lo, hi; double frac;
    qidx((double)thrp[0], 8192, lo, hi, frac);
    double thr1 = vv[2] * (1.0 - frac) + vv[3] * frac;
    float sw1 = 1.f / (1.f + __expf(-swp[1]));
    int row = 16 * t - 1 + tid;
    row = min(max(row, 0), 1023);
    m1s[tid] = (e1[b * 1024 + row] > thr1) ? sw1 : 0.f;
  }
  if (tid < 10) {
    int lo, hi; double frac;
    qidx((double)thrp[0], 4096, lo, hi, frac);
    double thr2 = vv[4] * (1.0 - frac) + vv[5] * frac;
    float sw2 = 1.f / (1.f + __expf(-swp[2]));
    int row = 8 * t - 1 + tid;
    row = min(max(row, 0), 511);
    m2s[tid] = (e2[b * 512 + row] > thr2) ? sw2 : 0.f;
  }
  __syncthreads();
  float sw3 = 1.f / (1.f + __expf(-swp[3]));
  float mix = (float)mixp[0];

  const float* xp = x + (size_t)b * N_ * C_ + c;

  // streaming Haar cascade: persistent detail halos + a3
  float d0[34], d1[18], d2[10], a3[6];
  float c0 = 0.f, c1 = 0.f, c2 = 0.f;
#pragma unroll
  for (int i = 0; i < 48; ++i) {
    int qrow = 32 * t - 8 + i;  // level-0 approx global row
    int r0 = min(max(2 * qrow, 0), N_ - 1);
    int r1 = min(max(2 * qrow + 1, 0), N_ - 1);
    float xa = xp[(size_t)r0 * C_];
    float xb = xp[(size_t)r1 * C_];
    float a0 = (xa + xb) * 0.5f;
    if (i >= 7 && i < 41) d0[i - 7] = (xa - xb) * 0.5f;  // rows 32t-1 .. 32t+32
    if ((i & 1) == 0)
      c0 = a0;
    else {
      int i1 = i >> 1;  // a1 row 16t-4+i1
      float a1 = (c0 + a0) * 0.5f;
      if (i1 >= 3 && i1 < 21) d1[i1 - 3] = (c0 - a0) * 0.5f;  // rows 16t-1..16t+16
      if ((i1 & 1) == 0)
        c1 = a1;
      else {
        int i2 = i1 >> 1;  // a2 row 8t-2+i2
        float a2 = (c1 + a1) * 0.5f;
        if (i2 >= 1 && i2 < 11) d2[i2 - 1] = (c1 - a1) * 0.5f;  // rows 8t-1..8t+8
        if ((i2 & 1) == 0)
          c2 = a2;
        else
          a3[i2 >> 1] = (c2 + a2) * 0.5f;  // rows 4t-1..4t+4
      }
    }
  }

  float rec256[6];
#pragma unroll
  for (int i = 0; i < 6; ++i) rec256[i] = a3[i] * sw3;

  // up 256->512 (+ masked d2). rows r = 8t-1+j (base odd).
  float rec512[10];
#pragma unroll
  for (int j = 0; j < 10; ++j) {
    float v;
    if ((j & 1) == 0) {  // r odd: out[2s+1] = .75 in[s] + .25 in[s+1]
      int s = 4 * t - 1 + (j >> 1);
      int sl = j >> 1;
      v = 0.75f * rec256[sl] + 0.25f * rec256[sl + 1];
      if (s == 255) v = rec256[sl];
    } else {  // r even: out[2s] = .25 in[s-1] + .75 in[s]
      int s = 4 * t + (j >> 1);
      int sl = (j >> 1) + 1;
      v = 0.25f * rec256[sl - 1] + 0.75f * rec256[sl];
      if (s == 0) v = rec256[sl];
    }
    rec512[j] = v + d2[j] * m2s[j];
  }

  // up 512->1024 (+ masked d1). rows p = 16t-1+j.
  float rec1024[18];
#pragma unroll
  for (int j = 0; j < 18; ++j) {
    float v;
    if ((j & 1) == 0) {
      int s = 8 * t - 1 + (j >> 1);
      int sl = j >> 1;
      v = 0.75f * rec512[sl] + 0.25f * rec512[sl + 1];
      if (s == 511) v = rec512[sl];
    } else {
      int s = 8 * t + (j >> 1);
      int sl = (j >> 1) + 1;
      v = 0.25f * rec512[sl - 1] + 0.75f * rec512[sl];
      if (s == 0) v = rec512[sl];
    }
    rec1024[j] = v + d1[j] * m1s[j];
  }

  // up 1024->2048 (+ masked d0). rows m = 32t-1+j.
  float rec2048[34];
#pragma unroll
  for (int j = 0; j < 34; ++j) {
    float v;
    if ((j & 1) == 0) {
      int s = 16 * t - 1 + (j >> 1);
      int sl = j >> 1;
      v = 0.75f * rec1024[sl] + 0.25f * rec1024[sl + 1];
      if (s == 1023) v = rec1024[sl];
    } else {
      int s = 16 * t + (j >> 1);
      int sl = (j >> 1) + 1;
      v = 0.25f * rec1024[sl - 1] + 0.75f * rec1024[sl];
      if (s == 0) v = rec1024[sl];
    }
    rec2048[j] = v + d0[j] * m0s[j];
  }

  // final up 2048->4096, scale, store. rows g = 64t+j (base even).
  float* op = out + ((size_t)(b * N_ + 64 * t)) * C_ + c;
#pragma unroll
  for (int j = 0; j < 64; ++j) {
    float v;
    if ((j & 1) == 0) {  // g even: out[2s] = .25 in[s-1] + .75 in[s]
      int s = 32 * t + (j >> 1);
      int sl = (j >> 1) + 1;
      v = 0.25f * rec2048[sl - 1] + 0.75f * rec2048[sl];
      if (s == 0) v = rec2048[sl];
    } else {  // g odd: out[2s+1] = .75 in[s] + .25 in[s+1]
      int s = 32 * t + (j >> 1);
      int sl = (j >> 1) + 1;
      v = 0.75f * rec2048[sl] + 0.25f * rec2048[sl + 1];
      if (s == 2047) v = rec2048[sl];
    }
    op[(size_t)j * C_] = v * mix;
  }
}

extern "C" void kernel_launch(void* const* d_in, const int* in_sizes, int n_in,
                              void* d_out, int out_size, void* d_ws, size_t ws_size,
                              hipStream_t stream) {
  const float* x = (const float*)d_in[0];
  const float* cw1 = (const float*)d_in[1];
  const float* cw2 = (const float*)d_in[2];
  const float* cw3 = (const float*)d_in[3];
  const float* thrp = (const float*)d_in[4];
  const float* sws = (const float*)d_in[5];
  const float* rw = (const float*)d_in[6];
  float* out = (float*)d_out;
  double* ws = (double*)d_ws;

  hipLaunchKernelGGL(k_energy, dim3(2048), dim3(256), 0, stream, x, ws);
  hipLaunchKernelGGL(k_select, dim3(4), dim3(1024), 0, stream, ws, ws + 30720,
                     ws + 30728, thrp, cw1, cw2, cw3, rw);
  hipLaunchKernelGGL(k_recon, dim3(2048), dim3(256), 0, stream, x, out, ws, sws,
                     thrp);
}